// Round 5
// baseline (1625.099 us; speedup 1.0000x reference)
//
#include <hip/hip_runtime.h>
#include <hip/hip_bf16.h>

#define NN 100000        // nodes per type
#define NE 1000000       // edges per relation
#define FI 128
#define FO 64
#define CHB 98           // ceil(NN/1024) scan chunks

typedef unsigned short u16;

__device__ __forceinline__ float bf2f(u16 u) {
    unsigned int v = ((unsigned int)u) << 16;
    return __uint_as_float(v);
}

// ---------------- projection + attention-logit kernel ----------------
__global__ __launch_bounds__(256) void proj_kernel(
    const float* __restrict__ x, const float* __restrict__ W, const float* __restrict__ b,
    const float* __restrict__ a0, const float* __restrict__ a1,
    const float* __restrict__ a2, const float* __restrict__ a3,
    u16* __restrict__ hout, float* __restrict__ al)
{
    __shared__ float Wl[FI * FO];
    for (int i = threadIdx.x; i < FI * FO; i += 256) Wl[i] = W[i];
    __syncthreads();

    const int lane = threadIdx.x & 63;
    const int wid  = threadIdx.x >> 6;
    const int gw   = blockIdx.x * 4 + wid;
    const int nw   = gridDim.x * 4;
    const int head = lane >> 4;

    const float bv  = b[lane];
    const float av0 = a0[lane];
    const float av1 = a1[lane];
    const float av2 = a2[lane];
    const float av3 = a3[lane];

    for (int n = gw; n < NN; n += nw) {
        const float x0 = x[n * FI + lane];
        const float x1 = x[n * FI + 64 + lane];
        float acc = bv;
#pragma unroll
        for (int k = 0; k < 64; ++k)
            acc = fmaf(__shfl(x0, k), Wl[k * FO + lane], acc);
#pragma unroll
        for (int k = 0; k < 64; ++k)
            acc = fmaf(__shfl(x1, k), Wl[(64 + k) * FO + lane], acc);

        __hip_bfloat16 hv = __float2bfloat16(acc);
        hout[n * FO + lane] = *(u16*)&hv;

        float p0 = acc * av0, p1 = acc * av1, p2 = acc * av2, p3 = acc * av3;
#pragma unroll
        for (int off = 1; off < 16; off <<= 1) {
            p0 += __shfl_xor(p0, off);
            p1 += __shfl_xor(p1, off);
            p2 += __shfl_xor(p2, off);
            p3 += __shfl_xor(p3, off);
        }
        if ((lane & 15) == 0) {
            al[0 * NN * 4 + n * 4 + head] = p0;
            al[1 * NN * 4 + n * 4 + head] = p1;
            al[2 * NN * 4 + n * 4 + head] = p2;
            al[3 * NN * 4 + n * 4 + head] = p3;
        }
    }
}

// ---------------- CSR build: histogram ----------------
__global__ __launch_bounds__(256) void hist_kernel(
    const int* __restrict__ ei_pt, const int* __restrict__ ei_tt,
    const int* __restrict__ ei_tp, const int* __restrict__ ei_pp,
    int* __restrict__ counts)
{
    const int rel = blockIdx.y;
    const int* ei = (rel == 0) ? ei_pt : (rel == 1) ? ei_tt : (rel == 2) ? ei_tp : ei_pp;
    int* cnt = counts + (size_t)rel * NN;
    const int stride = gridDim.x * 256;
    for (int e = blockIdx.x * 256 + threadIdx.x; e < NE; e += stride)
        atomicAdd(&cnt[ei[NE + e]], 1);
}

// ---------------- scan P1: per-chunk (1024 ints) partial sums ----------------
__global__ __launch_bounds__(256) void scan_part1(
    const int* __restrict__ counts, int* __restrict__ bsum)
{
    const int rel = blockIdx.y;
    const int b = blockIdx.x;
    const int idx = b * 1024 + threadIdx.x * 4;
    const int* cnt = counts + (size_t)rel * NN;
    int s = 0;
    if (idx < NN) { int4 c = *(const int4*)(cnt + idx); s = c.x + c.y + c.z + c.w; }
#pragma unroll
    for (int off = 1; off < 64; off <<= 1) s += __shfl_xor(s, off);
    __shared__ int ws[4];
    if ((threadIdx.x & 63) == 0) ws[threadIdx.x >> 6] = s;
    __syncthreads();
    if (threadIdx.x == 0) bsum[rel * CHB + b] = ws[0] + ws[1] + ws[2] + ws[3];
}

// ---------------- scan P2: exclusive-scan the 98 block sums (per rel), in place ----------------
__global__ __launch_bounds__(128) void scan_part2(int* __restrict__ bsum, int* __restrict__ offs)
{
    const int rel = blockIdx.x;
    int* bs = bsum + rel * CHB;
    __shared__ int sm[128];
    const int tid = threadIdx.x;
    int v = (tid < CHB) ? bs[tid] : 0;
    sm[tid] = v;
    __syncthreads();
    for (int off = 1; off < 128; off <<= 1) {
        int t = (tid >= off) ? sm[tid - off] : 0;
        __syncthreads();
        sm[tid] += t;
        __syncthreads();
    }
    if (tid < CHB) bs[tid] = sm[tid] - v;   // exclusive
    if (tid == 0) offs[(size_t)rel * (NN + 1) + NN] = NE;  // totals are known
}

// ---------------- scan P3: block-local exclusive scan + base; writes offs & cursor ----------------
__global__ __launch_bounds__(256) void scan_part3(
    const int* __restrict__ counts, const int* __restrict__ bsum,
    int* __restrict__ offs, int* __restrict__ cursor)
{
    const int rel = blockIdx.y;
    const int b = blockIdx.x;
    const int idx = b * 1024 + threadIdx.x * 4;
    const int* cnt = counts + (size_t)rel * NN;
    int* of = offs + (size_t)rel * (NN + 1);
    int* cu = cursor + (size_t)rel * NN;

    int4 c = make_int4(0, 0, 0, 0);
    if (idx < NN) c = *(const int4*)(cnt + idx);
    const int s = c.x + c.y + c.z + c.w;

    const int lane = threadIdx.x & 63;
    const int wid  = threadIdx.x >> 6;
    int incl = s;
#pragma unroll
    for (int off = 1; off < 64; off <<= 1) {
        int t = __shfl_up(incl, off);
        if (lane >= off) incl += t;
    }
    __shared__ int wsum[4];
    if (lane == 63) wsum[wid] = incl;
    __syncthreads();
    int wbase = 0;
    for (int w = 0; w < wid; ++w) wbase += wsum[w];

    const int base = bsum[rel * CHB + b] + wbase + (incl - s);
    if (idx < NN) {
        const int o0 = base;
        of[idx]     = o0;                   cu[idx]     = o0;
        of[idx + 1] = o0 + c.x;             cu[idx + 1] = o0 + c.x;
        of[idx + 2] = o0 + c.x + c.y;       cu[idx + 2] = o0 + c.x + c.y;
        of[idx + 3] = o0 + c.x + c.y + c.z; cu[idx + 3] = o0 + c.x + c.y + c.z;
    }
}

// ---------------- CSR build: scatter src into dst-bins ----------------
__global__ __launch_bounds__(256) void scatter_kernel(
    const int* __restrict__ ei_pt, const int* __restrict__ ei_tt,
    const int* __restrict__ ei_tp, const int* __restrict__ ei_pp,
    int* __restrict__ cursor, int* __restrict__ perm)
{
    const int rel = blockIdx.y;
    const int* ei = (rel == 0) ? ei_pt : (rel == 1) ? ei_tt : (rel == 2) ? ei_tp : ei_pp;
    int* cu = cursor + (size_t)rel * NN;
    int* pm = perm + (size_t)rel * NE;
    const int stride = gridDim.x * 256;
    for (int e = blockIdx.x * 256 + threadIdx.x; e < NE; e += stride) {
        const int src = ei[e];
        const int dst = ei[NE + e];
        const int pos = atomicAdd(&cu[dst], 1);
        pm[pos] = src;
    }
}

// ---------------- accumulate: wave per dst node; lane-parallel edge phase ----------------
// rel 0: pt -> trans r0 ; rel 1: tt -> trans r1 ; rel 2: tp -> place r0 ; rel 3: pp -> place r1
__global__ __launch_bounds__(256) void acc_kernel(
    const u16* __restrict__ hb_place, const u16* __restrict__ hb_trans,
    const float* __restrict__ al_place, const float* __restrict__ al_trans,
    const int* __restrict__ offs, const int* __restrict__ perm,
    const float* __restrict__ kW, const float* __restrict__ kb,
    float* __restrict__ outbuf, float* __restrict__ mean_acc)
{
    const int rel = blockIdx.y;
    const u16* hb; const float* als; const float* ald;
    if (rel == 0)      { hb = hb_place; als = al_place + 0 * NN * 4; ald = al_trans + 2 * NN * 4; }
    else if (rel == 1) { hb = hb_trans; als = al_trans + 1 * NN * 4; ald = al_trans + 3 * NN * 4; }
    else if (rel == 2) { hb = hb_trans; als = al_trans + 0 * NN * 4; ald = al_place + 2 * NN * 4; }
    else               { hb = hb_place; als = al_place + 1 * NN * 4; ald = al_place + 3 * NN * 4; }
    const int* of = offs + (size_t)rel * (NN + 1);
    const int* pm = perm + (size_t)rel * NE;
    float* ob = outbuf + (size_t)rel * NN * FO;

    __shared__ float kWl[FO * FO];
    for (int i = threadIdx.x; i < FO * FO; i += 256) kWl[i] = kW[i];
    __syncthreads();

    const int lane = threadIdx.x & 63;
    const int wid  = threadIdx.x >> 6;
    const int head = lane >> 4;
    const float kbv = kb[lane];

    float ts = 0.f;
    const int gw = blockIdx.x * 4 + wid;
    const int nw = gridDim.x * 4;
    for (int n = gw; n < NN; n += nw) {
        const int beg = of[n], end = of[n + 1];
        const float4 adv = *(const float4*)(ald + n * 4);
        float num = 0.f, den = 0.f;

        for (int c = beg; c < end; c += 64) {
            const int m = min(64, end - c);
            // phase A: lane j owns edge c+j — load src + als float4, compute 4 head exps
            int src = 0;
            float e0 = 0.f, e1 = 0.f, e2 = 0.f, e3 = 0.f;
            if (lane < m) {
                src = pm[c + lane];
                const float4 av = *(const float4*)(als + src * 4);
                float a0 = av.x + adv.x; a0 = a0 > 0.f ? a0 : 0.2f * a0;
                float a1 = av.y + adv.y; a1 = a1 > 0.f ? a1 : 0.2f * a1;
                float a2 = av.z + adv.z; a2 = a2 > 0.f ? a2 : 0.2f * a2;
                float a3 = av.w + adv.w; a3 = a3 > 0.f ? a3 : 0.2f * a3;
                e0 = __expf(a0); e1 = __expf(a1); e2 = __expf(a2); e3 = __expf(a3);
            }
            // denominator: reduce each head's exps across lanes
            float d0 = e0, d1 = e1, d2 = e2, d3 = e3;
#pragma unroll
            for (int off = 1; off < 64; off <<= 1) {
                d0 += __shfl_xor(d0, off);
                d1 += __shfl_xor(d1, off);
                d2 += __shfl_xor(d2, off);
                d3 += __shfl_xor(d3, off);
            }
            den += (head == 0) ? d0 : (head == 1) ? d1 : (head == 2) ? d2 : d3;

            // phase B: numerator — all addresses known, loads pipeline freely
#pragma unroll 4
            for (int j = 0; j < m; ++j) {
                const int sj = __builtin_amdgcn_readlane(src, j);
                const int w0 = __builtin_amdgcn_readlane(__float_as_int(e0), j);
                const int w1 = __builtin_amdgcn_readlane(__float_as_int(e1), j);
                const int w2 = __builtin_amdgcn_readlane(__float_as_int(e2), j);
                const int w3 = __builtin_amdgcn_readlane(__float_as_int(e3), j);
                const float w = __int_as_float((head == 0) ? w0 : (head == 1) ? w1 : (head == 2) ? w2 : w3);
                const float hv = bf2f(hb[(size_t)sj * FO + lane]);
                num = fmaf(hv, w, num);
            }
        }

        const float outv = fmaxf(num / (den + 1e-16f), 0.f);
        ob[(size_t)n * FO + lane] = outv;

        // fused semantic-attention partial: y = out_row @ kW + kb, ts += tanh(y)
        float y = kbv;
#pragma unroll
        for (int k = 0; k < 64; ++k) y = fmaf(__shfl(outv, k), kWl[k * FO + lane], y);
        ts += tanhf(y);
    }

    __shared__ float red[4][64];
    red[wid][lane] = ts;
    __syncthreads();
    if (wid == 0) {
        const float s = red[0][lane] + red[1][lane] + red[2][lane] + red[3][lane];
        unsafeAtomicAdd(&mean_acc[rel * 64 + lane], s);
    }
}

// ---------------- score: semantic attention weights ----------------
__global__ void score_kernel(const float* __restrict__ mean_acc, const float* __restrict__ q,
                             float* __restrict__ attn)
{
    const int lane = threadIdx.x;  // 64 threads
    const float qv = q[lane];
    float sc[4];
#pragma unroll
    for (int r = 0; r < 4; ++r) {
        float p = qv * mean_acc[r * 64 + lane] * (1.0f / (float)NN);
#pragma unroll
        for (int off = 1; off < 64; off <<= 1) p += __shfl_xor(p, off);
        sc[r] = p;
    }
    if (lane == 0) {
        float m = fmaxf(sc[0], sc[1]);
        float e0 = expf(sc[0] - m), e1 = expf(sc[1] - m);
        attn[0] = e0 / (e0 + e1);
        attn[1] = e1 / (e0 + e1);
        m = fmaxf(sc[2], sc[3]);
        float f0 = expf(sc[2] - m), f1 = expf(sc[3] - m);
        attn[2] = f0 / (f0 + f1);
        attn[3] = f1 / (f0 + f1);
    }
}

// ---------------- combine: out = attn0*out_r0 + attn1*out_r1 (float32 output) ----------------
__global__ __launch_bounds__(256) void combine_kernel(
    const float* __restrict__ outbuf, const float* __restrict__ attn, float* __restrict__ out)
{
    const int type = blockIdx.y;           // 0 = place (rels 2,3), 1 = trans (rels 0,1)
    const int r0 = (type == 0) ? 2 : 0;
    const float a0 = attn[r0], a1 = attn[r0 + 1];
    const float4* o0 = (const float4*)(outbuf + (size_t)r0 * NN * FO);
    const float4* o1 = (const float4*)(outbuf + (size_t)(r0 + 1) * NN * FO);
    float4* dst = (float4*)(out + (size_t)type * NN * FO);
    const int n4 = NN * FO / 4;
    const int stride = gridDim.x * 256;
    for (int i = blockIdx.x * 256 + threadIdx.x; i < n4; i += stride) {
        const float4 u = o0[i];
        const float4 w = o1[i];
        float4 r;
        r.x = a0 * u.x + a1 * w.x;
        r.y = a0 * u.y + a1 * w.y;
        r.z = a0 * u.z + a1 * w.z;
        r.w = a0 * u.w + a1 * w.w;
        dst[i] = r;
    }
}

extern "C" void kernel_launch(void* const* d_in, const int* in_sizes, int n_in,
                              void* d_out, int out_size, void* d_ws, size_t ws_size,
                              hipStream_t stream)
{
    const float* x_place = (const float*)d_in[0];
    const float* x_trans = (const float*)d_in[1];
    const float* W_place = (const float*)d_in[2];
    const float* b_place = (const float*)d_in[3];
    const float* W_trans = (const float*)d_in[4];
    const float* b_trans = (const float*)d_in[5];
    const float* as_pt = (const float*)d_in[6];
    const float* ad_pt = (const float*)d_in[7];
    const float* as_tp = (const float*)d_in[8];
    const float* ad_tp = (const float*)d_in[9];
    const float* as_pp = (const float*)d_in[10];
    const float* ad_pp = (const float*)d_in[11];
    const float* as_tt = (const float*)d_in[12];
    const float* ad_tt = (const float*)d_in[13];
    const float* q  = (const float*)d_in[14];
    const float* kW = (const float*)d_in[15];
    const float* kb = (const float*)d_in[16];
    const int* ei_pt = (const int*)d_in[17];
    const int* ei_tp = (const int*)d_in[18];
    const int* ei_pp = (const int*)d_in[19];
    const int* ei_tt = (const int*)d_in[20];

    // ---- workspace layout ----
    char* ws = (char*)d_ws;
    u16* hb_place = (u16*)ws;                                     // NN*64 bf16 = 12.8 MB
    u16* hb_trans = hb_place + (size_t)NN * FO;                   // 12.8 MB
    float* al_place = (float*)(hb_trans + (size_t)NN * FO);       // 4*NN*4 f32 = 6.4 MB
    float* al_trans = al_place + 4 * (size_t)NN * 4;              // 6.4 MB
    float* outbuf = al_trans + 4 * (size_t)NN * 4;                // 4*NN*64 f32 = 102.4 MB
    int* counts = (int*)(outbuf + 4 * (size_t)NN * FO);           // 4*NN int = 1.6 MB
    float* mean_acc = (float*)(counts + 4 * (size_t)NN);          // 256 f32
    float* attn = mean_acc + 256;                                 // 4 f32
    int* offs = (int*)(attn + 4);                                 // 4*(NN+1) int
    int* cursor = offs + 4 * (size_t)(NN + 1);                    // 4*NN int
    int* perm = cursor + 4 * (size_t)NN;                          // 4*NE int = 16 MB
    int* bsum = perm + 4 * (size_t)NE;                            // 4*CHB int

    // zero counts + mean_acc (+attn) in one shot
    hipMemsetAsync(counts, 0, (4 * (size_t)NN + 256 + 4) * sizeof(int), stream);

    // place node roles: src of pt, src of pp, dst of tp, dst of pp
    proj_kernel<<<2048, 256, 0, stream>>>(x_place, W_place, b_place,
                                          as_pt, as_pp, ad_tp, ad_pp,
                                          hb_place, al_place);
    // trans node roles: src of tp, src of tt, dst of pt, dst of tt
    proj_kernel<<<2048, 256, 0, stream>>>(x_trans, W_trans, b_trans,
                                          as_tp, as_tt, ad_pt, ad_tt,
                                          hb_trans, al_trans);

    hist_kernel<<<dim3(2048, 4), 256, 0, stream>>>(ei_pt, ei_tt, ei_tp, ei_pp, counts);
    scan_part1<<<dim3(CHB, 4), 256, 0, stream>>>(counts, bsum);
    scan_part2<<<4, 128, 0, stream>>>(bsum, offs);
    scan_part3<<<dim3(CHB, 4), 256, 0, stream>>>(counts, bsum, offs, cursor);
    scatter_kernel<<<dim3(2048, 4), 256, 0, stream>>>(ei_pt, ei_tt, ei_tp, ei_pp, cursor, perm);

    acc_kernel<<<dim3(1024, 4), 256, 0, stream>>>(hb_place, hb_trans, al_place, al_trans,
                                                  offs, perm, kW, kb, outbuf, mean_acc);

    score_kernel<<<1, 64, 0, stream>>>(mean_acc, q, attn);

    combine_kernel<<<dim3(1024, 2), 256, 0, stream>>>(outbuf, attn, (float*)d_out);
}